// Round 7
// baseline (169.202 us; speedup 1.0000x reference)
//
#include <hip/hip_runtime.h>
#include <hip/hip_cooperative_groups.h>

namespace cg = cooperative_groups;

#define B_ 16
#define C_ 64
#define N_ 16384          // 128*128
#define KCH 32            // gram chunks per batch -> 512 blocks total
#define CPB 512           // columns per gram chunk
#define SROW 72           // Xt row stride in bf16 (pad 64 -> 72)

typedef __attribute__((ext_vector_type(8))) short bf16x8;
typedef __attribute__((ext_vector_type(4))) float f32x4;
typedef __attribute__((ext_vector_type(4))) short s16x4;

// fp32 -> bf16 round-to-nearest-even, bit form (known-good)
__device__ __forceinline__ short f2bf(float f) {
    unsigned int u = __float_as_uint(f);
    unsigned int r = (u + 0x7FFFu + ((u >> 16) & 1u)) >> 16;
    return (short)r;
}

__device__ __forceinline__ bf16x8 cvt8(float4 lo, float4 hi) {
    bf16x8 r;
    r[0] = f2bf(lo.x); r[1] = f2bf(lo.y); r[2] = f2bf(lo.z); r[3] = f2bf(lo.w);
    r[4] = f2bf(hi.x); r[5] = f2bf(hi.y); r[6] = f2bf(hi.z); r[7] = f2bf(hi.w);
    return r;
}

// Phase-exclusive LDS: 36.9 KiB max -> 2 blocks/CU (72 KiB < 160 KiB)
union __align__(16) SharedU {
    float red[2][4096];                              // phase 1: 32 KiB
    unsigned short Xt[256][SROW];                    // phase 3: 36 KiB
    struct { float Gs[C_][17]; float Ws[C_][65]; } rm;  // phase 2: 21 KiB
};

// ONE cooperative kernel, 512 blocks x 256 threads, 2 blocks/CU co-resident.
// phase 1 (all blocks):   gram partials (R4-verified body)
// phase 2 (blocks 0..63): reduce + decode + apply W -> bf16 M
// phase 3 (all blocks):   out = M @ X, two 256-col slices per block
__global__ __launch_bounds__(256, 2)
void fused_kernel(const float* __restrict__ x, const float* __restrict__ W,
                  float* __restrict__ gpart, unsigned short* __restrict__ Mbf,
                  float* __restrict__ out) {
    __shared__ SharedU sh;
    const int t = threadIdx.x, l = t & 63, w = t >> 6;
    const int bid = blockIdx.x;
    const int row = l & 15, kg = l >> 4;

    // ================= phase 1: gram partials =================
    {
        const int b = bid >> 5, ch = bid & 31;
        const float* xb = x + (size_t)b * (C_ * (size_t)N_);
        const int kbase = ch * CPB + w * (CPB / 4);

        f32x4 acc[4][4] = {};
        float4 raw[2][4][2];

        #pragma unroll
        for (int g = 0; g < 4; ++g) {
            const float* p = xb + (size_t)(16 * g + row) * N_ + kbase + kg * 8;
            raw[0][g][0] = *(const float4*)p;
            raw[0][g][1] = *(const float4*)(p + 4);
        }

        #pragma unroll
        for (int ks = 0; ks < 4; ++ks) {
            const int cb = ks & 1, nb = cb ^ 1;
            if (ks < 3) {
                #pragma unroll
                for (int g = 0; g < 4; ++g) {
                    const float* p = xb + (size_t)(16 * g + row) * N_ +
                                     kbase + (ks + 1) * 32 + kg * 8;
                    raw[nb][g][0] = *(const float4*)p;
                    raw[nb][g][1] = *(const float4*)(p + 4);
                }
            }
            bf16x8 fr[4];
            #pragma unroll
            for (int g = 0; g < 4; ++g) fr[g] = cvt8(raw[cb][g][0], raw[cb][g][1]);
            #pragma unroll
            for (int gc = 0; gc < 4; ++gc)
                #pragma unroll
                for (int gd = 0; gd < 4; ++gd)
                    acc[gc][gd] = __builtin_amdgcn_mfma_f32_16x16x32_bf16(
                        fr[gc], fr[gd], acc[gc][gd], 0, 0, 0);
        }

        // two-phase block reduce: waves 0,1 write; waves 2,3 add; all sum halves
        if (w < 2) {
            #pragma unroll
            for (int gc = 0; gc < 4; ++gc)
                #pragma unroll
                for (int gd = 0; gd < 4; ++gd)
                    *(f32x4*)&sh.red[w][(gc * 4 + gd) * 256 + l * 4] = acc[gc][gd];
        }
        __syncthreads();
        if (w >= 2) {
            #pragma unroll
            for (int gc = 0; gc < 4; ++gc)
                #pragma unroll
                for (int gd = 0; gd < 4; ++gd) {
                    float* p = &sh.red[w - 2][(gc * 4 + gd) * 256 + l * 4];
                    f32x4 v = *(f32x4*)p;
                    *(f32x4*)p = v + acc[gc][gd];
                }
        }
        __syncthreads();

        f32x4* dst = (f32x4*)(gpart + ((size_t)b * KCH + ch) * 4096);
        const f32x4* r0 = (const f32x4*)sh.red[0];
        const f32x4* r1 = (const f32x4*)sh.red[1];
        #pragma unroll
        for (int j = 0; j < 4; ++j)
            dst[j * 256 + t] = r0[j * 256 + t] + r1[j * 256 + t];
    }

    cg::this_grid().sync();

    // ================= phase 2: reduce + W -> M (blocks 0..63) =================
    if (bid < 64) {
        const int gd = bid & 3, b = bid >> 2;

        for (int i = t; i < C_ * C_; i += 256) sh.rm.Ws[i >> 6][i & 63] = W[i];

        const int f = t;  // flat in-tile index = lane*4 + reg
        #pragma unroll
        for (int gc = 0; gc < 4; ++gc) {
            const float* p = gpart + (size_t)b * KCH * 4096 + (gc * 4 + gd) * 256 + f;
            float s0 = 0.f, s1 = 0.f, s2 = 0.f, s3 = 0.f;
            #pragma unroll 2
            for (int ch = 0; ch < KCH; ch += 4) {
                s0 += p[(size_t)(ch + 0) * 4096];
                s1 += p[(size_t)(ch + 1) * 4096];
                s2 += p[(size_t)(ch + 2) * 4096];
                s3 += p[(size_t)(ch + 3) * 4096];
            }
            const int c = gc * 16 + (f >> 6) * 4 + (f & 3);
            const int dloc = (f >> 2) & 15;
            sh.rm.Gs[c][dloc] = (s0 + s1) + (s2 + s3);
        }
        __syncthreads();

        const int o = t & 63, g2 = t >> 6;
        const float invN = 1.0f / (float)N_;
        #pragma unroll
        for (int j = 0; j < 4; ++j) {
            const int dloc = g2 * 4 + j;
            float s = 0.f;
            #pragma unroll
            for (int c = 0; c < C_; ++c) s = fmaf(sh.rm.Ws[o][c], sh.rm.Gs[c][dloc], s);
            Mbf[((size_t)b * C_ + o) * C_ + gd * 16 + dloc] = (unsigned short)f2bf(s * invN);
        }
    }

    cg::this_grid().sync();

    // ================= phase 3: out = M @ X, two slices =================
    {
        const int s_base = bid * 2;
        const int b = s_base >> 6;                 // 64 slices per batch; both slices same b
        const float* xb = x + (size_t)b * (C_ * (size_t)N_);
        float* ob = out + (size_t)b * (C_ * (size_t)N_);

        // A fragments: lane l -> M[16g+row][ks*32 + kg*8 + j]
        bf16x8 afrag[2][4];
        #pragma unroll
        for (int ks = 0; ks < 2; ++ks)
            #pragma unroll
            for (int g = 0; g < 4; ++g)
                afrag[ks][g] = *(const bf16x8*)((const short*)Mbf +
                    ((size_t)b * C_ + 16 * g + row) * C_ + ks * 32 + kg * 8);

        const int d0 = (t & 15) * 4, nb2 = (t >> 4) * 16;

        #pragma unroll
        for (int i = 0; i < 2; ++i) {
            const int n0 = ((s_base + i) & 63) * 256;
            if (i) __syncthreads();   // protect Xt reuse across slices

            #pragma unroll
            for (int p = 0; p < 2; ++p) {
                const int n8 = nb2 + p * 8;
                float a[4][8];
                #pragma unroll
                for (int r = 0; r < 4; ++r) {
                    const float* src = xb + (size_t)(d0 + r) * N_ + n0 + n8;
                    float4 q0 = *(const float4*)src;
                    float4 q1 = *(const float4*)(src + 4);
                    a[r][0] = q0.x; a[r][1] = q0.y; a[r][2] = q0.z; a[r][3] = q0.w;
                    a[r][4] = q1.x; a[r][5] = q1.y; a[r][6] = q1.z; a[r][7] = q1.w;
                }
                #pragma unroll
                for (int j = 0; j < 8; ++j) {
                    s16x4 pk;
                    pk[0] = f2bf(a[0][j]); pk[1] = f2bf(a[1][j]);
                    pk[2] = f2bf(a[2][j]); pk[3] = f2bf(a[3][j]);
                    *(s16x4*)&sh.Xt[n8 + j][d0] = pk;
                }
            }
            __syncthreads();

            #pragma unroll
            for (int nt = 0; nt < 4; ++nt) {
                const int ntile = w * 4 + nt;
                bf16x8 bfrag0 = *(const bf16x8*)&sh.Xt[ntile * 16 + row][kg * 8];
                bf16x8 bfrag1 = *(const bf16x8*)&sh.Xt[ntile * 16 + row][32 + kg * 8];
                #pragma unroll
                for (int g = 0; g < 4; ++g) {
                    f32x4 acc = {};
                    acc = __builtin_amdgcn_mfma_f32_16x16x32_bf16(afrag[0][g], bfrag0, acc, 0, 0, 0);
                    acc = __builtin_amdgcn_mfma_f32_16x16x32_bf16(afrag[1][g], bfrag1, acc, 0, 0, 0);
                    #pragma unroll
                    for (int r = 0; r < 4; ++r)
                        ob[(size_t)(16 * g + 4 * kg + r) * N_ + n0 + ntile * 16 + row] = acc[r];
                }
            }
        }
    }
}

extern "C" void kernel_launch(void* const* d_in, const int* in_sizes, int n_in,
                              void* d_out, int out_size, void* d_ws, size_t ws_size,
                              hipStream_t stream) {
    const float* x = (const float*)d_in[0];   // [16,64,128,128] fp32
    const float* w = (const float*)d_in[1];   // [64,64] fp32
    float* out = (float*)d_out;               // [16,64,128,128] fp32

    float* gpart = (float*)d_ws;                                      // 8 MiB
    unsigned short* Mbf = (unsigned short*)(gpart + (size_t)B_ * KCH * 4096);  // 128 KiB

    void* args[] = { (void*)&x, (void*)&w, (void*)&gpart, (void*)&Mbf, (void*)&out };
    hipLaunchCooperativeKernel((const void*)fused_kernel, dim3(B_ * KCH), dim3(256),
                               args, 0, stream);
}

// Round 9
// 53.830 us; speedup vs baseline: 3.1433x; 3.1433x over previous
//
#include <hip/hip_runtime.h>

#define B_ 16
#define C_ 64
#define N_ 16384          // 128*128
#define KCH 32            // gram chunks per batch -> 512 blocks
#define CPB 512           // columns per gram block (N_/KCH)
#define SROW 72           // Xt row stride in bf16 (pad 64 -> 72)

typedef __attribute__((ext_vector_type(8))) short bf16x8;
typedef __attribute__((ext_vector_type(4))) float f32x4;
typedef __attribute__((ext_vector_type(4))) short s16x4;

// fp32 -> bf16 round-to-nearest-even, bit form (known-good)
__device__ __forceinline__ short f2bf(float f) {
    unsigned int u = __float_as_uint(f);
    unsigned int r = (u + 0x7FFFu + ((u >> 16) & 1u)) >> 16;
    return (short)r;
}

__device__ __forceinline__ bf16x8 cvt8(float4 lo, float4 hi) {
    bf16x8 r;
    r[0] = f2bf(lo.x); r[1] = f2bf(lo.y); r[2] = f2bf(lo.z); r[3] = f2bf(lo.w);
    r[4] = f2bf(hi.x); r[5] = f2bf(hi.y); r[6] = f2bf(hi.z); r[7] = f2bf(hi.w);
    return r;
}

// -------- pass 1: per-(batch, k-chunk) partial gram via bf16 MFMA --------
// EXACT round-4 body (best verified): 4 waves/block, wave w owns columns
// [ch*512 + w*128, +128), 2-deep double-buffered raw float4 load registers.
__global__ __launch_bounds__(256)
void gram_kernel(const float* __restrict__ x, float* __restrict__ gpart) {
    __shared__ float red[2][4096];   // 32 KiB two-phase reduce buffer
    const int t = threadIdx.x, l = t & 63, w = t >> 6;
    const int b = blockIdx.y, ch = blockIdx.x;
    const float* xb = x + (size_t)b * (C_ * (size_t)N_);
    const int row = l & 15, kg = l >> 4;
    const int kbase = ch * CPB + w * (CPB / 4);

    f32x4 acc[4][4] = {};
    float4 raw[2][4][2];

    // preload k-step 0
    #pragma unroll
    for (int g = 0; g < 4; ++g) {
        const float* p = xb + (size_t)(16 * g + row) * N_ + kbase + kg * 8;
        raw[0][g][0] = *(const float4*)p;
        raw[0][g][1] = *(const float4*)(p + 4);
    }

    #pragma unroll
    for (int ks = 0; ks < 4; ++ks) {
        const int cb = ks & 1, nb = cb ^ 1;
        if (ks < 3) {   // issue next k-step's 8 loads before touching current
            #pragma unroll
            for (int g = 0; g < 4; ++g) {
                const float* p = xb + (size_t)(16 * g + row) * N_ +
                                 kbase + (ks + 1) * 32 + kg * 8;
                raw[nb][g][0] = *(const float4*)p;
                raw[nb][g][1] = *(const float4*)(p + 4);
            }
        }
        bf16x8 fr[4];
        #pragma unroll
        for (int g = 0; g < 4; ++g) fr[g] = cvt8(raw[cb][g][0], raw[cb][g][1]);
        #pragma unroll
        for (int gc = 0; gc < 4; ++gc)
            #pragma unroll
            for (int gd = 0; gd < 4; ++gd)
                acc[gc][gd] = __builtin_amdgcn_mfma_f32_16x16x32_bf16(
                    fr[gc], fr[gd], acc[gc][gd], 0, 0, 0);
    }

    // two-phase block reduce: waves 0,1 write; waves 2,3 add; all sum halves.
    if (w < 2) {
        #pragma unroll
        for (int gc = 0; gc < 4; ++gc)
            #pragma unroll
            for (int gd = 0; gd < 4; ++gd)
                *(f32x4*)&red[w][(gc * 4 + gd) * 256 + l * 4] = acc[gc][gd];
    }
    __syncthreads();
    if (w >= 2) {
        #pragma unroll
        for (int gc = 0; gc < 4; ++gc)
            #pragma unroll
            for (int gd = 0; gd < 4; ++gd) {
                float* p = &red[w - 2][(gc * 4 + gd) * 256 + l * 4];
                f32x4 v = *(f32x4*)p;
                *(f32x4*)p = v + acc[gc][gd];
            }
    }
    __syncthreads();

    f32x4* dst = (f32x4*)(gpart + ((size_t)b * KCH + ch) * 4096);
    const f32x4* r0 = (const f32x4*)red[0];
    const f32x4* r1 = (const f32x4*)red[1];
    #pragma unroll
    for (int j = 0; j < 4; ++j)
        dst[j * 256 + t] = r0[j * 256 + t] + r1[j * 256 + t];
}

// -------- pass 2a: reduce chunk partials, fully coalesced (R4 exact) --------
__global__ __launch_bounds__(256)
void reduce_kernel(const float* __restrict__ gpart, float* __restrict__ G) {
    const int gid = blockIdx.x * 256 + threadIdx.x;   // 0..65535
    const int b = gid >> 12, e = gid & 4095;
    const float* p = gpart + ((size_t)b * KCH) * 4096 + e;
    float s0 = 0.f, s1 = 0.f, s2 = 0.f, s3 = 0.f;
    #pragma unroll
    for (int ch = 0; ch < KCH; ch += 4) {
        s0 += p[(size_t)(ch + 0) * 4096];
        s1 += p[(size_t)(ch + 1) * 4096];
        s2 += p[(size_t)(ch + 2) * 4096];
        s3 += p[(size_t)(ch + 3) * 4096];
    }
    G[gid] = (s0 + s1) + (s2 + s3);
}

// -------- pass 2b (tiny): decode C-layout, apply W, emit bf16 M (R4 exact) --------
__global__ __launch_bounds__(256)
void m_kernel(const float* __restrict__ W, const float* __restrict__ G,
              unsigned short* __restrict__ Mbf) {
    __shared__ float Gs[C_][17];   // [c][dloc]
    __shared__ float Ws[C_][65];   // [o][c]
    const int gd = blockIdx.x, b = blockIdx.y, t = threadIdx.x;

    for (int i = t; i < C_ * C_; i += 256) Ws[i >> 6][i & 63] = W[i];

    const int f = t;  // flat in-tile index = lane*4 + reg
    #pragma unroll
    for (int gc = 0; gc < 4; ++gc) {
        float s = G[(size_t)b * 4096 + (gc * 4 + gd) * 256 + f];
        const int c = gc * 16 + (f >> 6) * 4 + (f & 3);
        const int dloc = (f >> 2) & 15;
        Gs[c][dloc] = s;
    }
    __syncthreads();

    const int o = t & 63, g2 = t >> 6;
    const float invN = 1.0f / (float)N_;
    #pragma unroll
    for (int j = 0; j < 4; ++j) {
        const int dloc = g2 * 4 + j;
        float s = 0.f;
        #pragma unroll
        for (int c = 0; c < C_; ++c) s = fmaf(Ws[o][c], Gs[c][dloc], s);
        Mbf[((size_t)b * C_ + o) * C_ + gd * 16 + dloc] = (unsigned short)f2bf(s * invN);
    }
}

// -------- pass 3: out_b = M_b @ X_b via bf16 MFMA, OPERAND-SWAPPED --------
// Same fragments as R4 (mfrag = M[o][d], xfrag = Xt[n][d] from LDS) but
// called as mfma(xfrag, mfrag): A-rows = n, B-cols = o. The fragment
// register layouts are identical either way; only D's interpretation flips:
// lane's 4 acc values = 4 CONSECUTIVE n at fixed o -> ONE dwordx4 store
// (was 4 scalar stores). Stores nontemporal (out is terminal; keep x in L3).
__global__ __launch_bounds__(256, 4)
void out_kernel(const float* __restrict__ x, const unsigned short* __restrict__ Mbf,
                float* __restrict__ out) {
    __shared__ unsigned short Xt[256][SROW];   // 36 KiB
    const int t = threadIdx.x, l = t & 63, w = t >> 6;
    const int b = blockIdx.y, n0 = blockIdx.x * 256;
    const float* xb = x + (size_t)b * (C_ * (size_t)N_);
    const int row = l & 15, kg = l >> 4;

    // M fragments: lane l -> M[16g+row][ks*32 + kg*8 + j]  (used as B operand)
    bf16x8 mfrag[2][4];
    #pragma unroll
    for (int ks = 0; ks < 2; ++ks)
        #pragma unroll
        for (int g = 0; g < 4; ++g)
            mfrag[ks][g] = *(const bf16x8*)((const short*)Mbf +
                ((size_t)b * C_ + 16 * g + row) * C_ + ks * 32 + kg * 8);

    // stage+transpose: thread t -> d-quad d0 = (t&15)*4, n-block = (t>>4)*16,
    // two 8-n halves to bound register pressure; ds_write_b64 packs 4 d's.
    const int d0 = (t & 15) * 4, nb2 = (t >> 4) * 16;
    #pragma unroll
    for (int p = 0; p < 2; ++p) {
        const int n8 = nb2 + p * 8;
        float a[4][8];
        #pragma unroll
        for (int r = 0; r < 4; ++r) {
            const float* src = xb + (size_t)(d0 + r) * N_ + n0 + n8;
            float4 q0 = *(const float4*)src;
            float4 q1 = *(const float4*)(src + 4);
            a[r][0] = q0.x; a[r][1] = q0.y; a[r][2] = q0.z; a[r][3] = q0.w;
            a[r][4] = q1.x; a[r][5] = q1.y; a[r][6] = q1.z; a[r][7] = q1.w;
        }
        #pragma unroll
        for (int j = 0; j < 8; ++j) {
            s16x4 pk;
            pk[0] = f2bf(a[0][j]); pk[1] = f2bf(a[1][j]);
            pk[2] = f2bf(a[2][j]); pk[3] = f2bf(a[3][j]);
            *(s16x4*)&Xt[n8 + j][d0] = pk;
        }
    }
    __syncthreads();

    float* ob = out + (size_t)b * (C_ * (size_t)N_);
    #pragma unroll
    for (int nt = 0; nt < 4; ++nt) {
        const int ntile = w * 4 + nt;
        bf16x8 xfrag0 = *(const bf16x8*)&Xt[ntile * 16 + row][kg * 8];
        bf16x8 xfrag1 = *(const bf16x8*)&Xt[ntile * 16 + row][32 + kg * 8];
        #pragma unroll
        for (int g = 0; g < 4; ++g) {
            f32x4 acc = {};
            acc = __builtin_amdgcn_mfma_f32_16x16x32_bf16(xfrag0, mfrag[0][g], acc, 0, 0, 0);
            acc = __builtin_amdgcn_mfma_f32_16x16x32_bf16(xfrag1, mfrag[1][g], acc, 0, 0, 0);
            // D: row = n-local = 4*kg + r, col = o-local = row(l&15)
            // lane stores out[16g + (l&15)][n0 + ntile*16 + 4*kg .. +3] as dwordx4
            __builtin_nontemporal_store(acc,
                (f32x4*)&ob[(size_t)(16 * g + row) * N_ + n0 + ntile * 16 + 4 * kg]);
        }
    }
}

extern "C" void kernel_launch(void* const* d_in, const int* in_sizes, int n_in,
                              void* d_out, int out_size, void* d_ws, size_t ws_size,
                              hipStream_t stream) {
    const float* x = (const float*)d_in[0];   // [16,64,128,128] fp32
    const float* w = (const float*)d_in[1];   // [64,64] fp32
    float* out = (float*)d_out;               // [16,64,128,128] fp32

    float* gpart = (float*)d_ws;                                      // 8 MiB
    float* G = gpart + (size_t)B_ * KCH * 4096;                       // 256 KiB
    unsigned short* Mbf = (unsigned short*)(G + (size_t)B_ * 4096);   // 128 KiB

    gram_kernel<<<dim3(KCH, B_), 256, 0, stream>>>(x, gpart);
    reduce_kernel<<<dim3((B_ * 4096) / 256), 256, 0, stream>>>(gpart, G);
    m_kernel<<<dim3(4, B_), 256, 0, stream>>>(w, G, Mbf);
    out_kernel<<<dim3(N_ / 256, B_), 256, 0, stream>>>(x, Mbf, out);
}

// Round 10
// 51.742 us; speedup vs baseline: 3.2701x; 1.0403x over previous
//
#include <hip/hip_runtime.h>
#include <hip/hip_bf16.h>

#define B_ 16
#define C_ 64
#define N_ 16384          // 128*128
#define KCH 32            // gram chunks per batch -> 512 blocks
#define CPB 512           // columns per gram block (N_/KCH)
#define SROW 72           // Xt row stride in bf16 (pad 64 -> 72)

typedef __attribute__((ext_vector_type(8))) short bf16x8;
typedef __attribute__((ext_vector_type(4))) float f32x4;
typedef __attribute__((ext_vector_type(4))) short s16x4;

// fp32 -> bf16 RNE via HW cvt: compiler fuses pairs into v_cvt_pk_bf16_f32
// (1 inst / 2 elems vs ~7 for the bit-form). Numerics identical (RNE),
// verified in R5 (absmax 0.015625 both ways).
__device__ __forceinline__ short f2bf(float f) {
    return (short)__bfloat16_as_ushort(__float2bfloat16(f));
}

__device__ __forceinline__ bf16x8 cvt8(float4 lo, float4 hi) {
    bf16x8 r;
    r[0] = f2bf(lo.x); r[1] = f2bf(lo.y); r[2] = f2bf(lo.z); r[3] = f2bf(lo.w);
    r[4] = f2bf(hi.x); r[5] = f2bf(hi.y); r[6] = f2bf(hi.z); r[7] = f2bf(hi.w);
    return r;
}

// -------- pass 1: per-(batch, k-chunk) partial gram via bf16 MFMA --------
// R9 body (best verified): 4 waves/block, wave w owns columns
// [ch*512 + w*128, +128), 2-deep double-buffered raw float4 load registers.
__global__ __launch_bounds__(256)
void gram_kernel(const float* __restrict__ x, float* __restrict__ gpart) {
    __shared__ float red[2][4096];   // 32 KiB two-phase reduce buffer
    const int t = threadIdx.x, l = t & 63, w = t >> 6;
    const int b = blockIdx.y, ch = blockIdx.x;
    const float* xb = x + (size_t)b * (C_ * (size_t)N_);
    const int row = l & 15, kg = l >> 4;
    const int kbase = ch * CPB + w * (CPB / 4);

    f32x4 acc[4][4] = {};
    float4 raw[2][4][2];

    // preload k-step 0
    #pragma unroll
    for (int g = 0; g < 4; ++g) {
        const float* p = xb + (size_t)(16 * g + row) * N_ + kbase + kg * 8;
        raw[0][g][0] = *(const float4*)p;
        raw[0][g][1] = *(const float4*)(p + 4);
    }

    #pragma unroll
    for (int ks = 0; ks < 4; ++ks) {
        const int cb = ks & 1, nb = cb ^ 1;
        if (ks < 3) {   // issue next k-step's 8 loads before touching current
            #pragma unroll
            for (int g = 0; g < 4; ++g) {
                const float* p = xb + (size_t)(16 * g + row) * N_ +
                                 kbase + (ks + 1) * 32 + kg * 8;
                raw[nb][g][0] = *(const float4*)p;
                raw[nb][g][1] = *(const float4*)(p + 4);
            }
        }
        bf16x8 fr[4];
        #pragma unroll
        for (int g = 0; g < 4; ++g) fr[g] = cvt8(raw[cb][g][0], raw[cb][g][1]);
        #pragma unroll
        for (int gc = 0; gc < 4; ++gc)
            #pragma unroll
            for (int gd = 0; gd < 4; ++gd)
                acc[gc][gd] = __builtin_amdgcn_mfma_f32_16x16x32_bf16(
                    fr[gc], fr[gd], acc[gc][gd], 0, 0, 0);
    }

    // two-phase block reduce: waves 0,1 write; waves 2,3 add; all sum halves.
    if (w < 2) {
        #pragma unroll
        for (int gc = 0; gc < 4; ++gc)
            #pragma unroll
            for (int gd = 0; gd < 4; ++gd)
                *(f32x4*)&red[w][(gc * 4 + gd) * 256 + l * 4] = acc[gc][gd];
    }
    __syncthreads();
    if (w >= 2) {
        #pragma unroll
        for (int gc = 0; gc < 4; ++gc)
            #pragma unroll
            for (int gd = 0; gd < 4; ++gd) {
                float* p = &red[w - 2][(gc * 4 + gd) * 256 + l * 4];
                f32x4 v = *(f32x4*)p;
                *(f32x4*)p = v + acc[gc][gd];
            }
    }
    __syncthreads();

    f32x4* dst = (f32x4*)(gpart + ((size_t)b * KCH + ch) * 4096);
    const f32x4* r0 = (const f32x4*)red[0];
    const f32x4* r1 = (const f32x4*)red[1];
    #pragma unroll
    for (int j = 0; j < 4; ++j)
        dst[j * 256 + t] = r0[j * 256 + t] + r1[j * 256 + t];
}

// -------- pass 2 (merged reduce+m, FULL load ILP): --------
// grid (4, B). R6's fused version was latency-bound (8 loads in flight);
// here the 32-chunk reduction is FULLY unrolled -> 32 independent loads
// per gc (2 latency rounds instead of ~8 on a mostly-idle device).
__global__ __launch_bounds__(256)
void rm_kernel(const float* __restrict__ W, const float* __restrict__ gpart,
               unsigned short* __restrict__ Mbf) {
    __shared__ float Gs[C_][17];   // [c][dloc]
    __shared__ float Ws[C_][65];   // [o][c]
    const int gd = blockIdx.x, b = blockIdx.y, t = threadIdx.x;

    for (int i = t; i < C_ * C_; i += 256) Ws[i >> 6][i & 63] = W[i];

    const int f = t;  // flat in-tile index = lane*4 + reg
    #pragma unroll
    for (int gc = 0; gc < 4; ++gc) {
        const float* p = gpart + (size_t)b * KCH * 4096 + (gc * 4 + gd) * 256 + f;
        float v[KCH];
        #pragma unroll
        for (int ch = 0; ch < KCH; ++ch)           // 32 loads, all in flight
            v[ch] = p[(size_t)ch * 4096];
        float s = 0.f;
        #pragma unroll
        for (int ch = 0; ch < KCH; ch += 4)        // 4-chain tree sum
            s += ((v[ch] + v[ch + 1]) + (v[ch + 2] + v[ch + 3]));
        const int c = gc * 16 + (f >> 6) * 4 + (f & 3);
        const int dloc = (f >> 2) & 15;
        Gs[c][dloc] = s;
    }
    __syncthreads();

    const int o = t & 63, g2 = t >> 6;
    const float invN = 1.0f / (float)N_;
    #pragma unroll
    for (int j = 0; j < 4; ++j) {
        const int dloc = g2 * 4 + j;
        float s = 0.f;
        #pragma unroll
        for (int c = 0; c < C_; ++c) s = fmaf(Ws[o][c], Gs[c][dloc], s);
        Mbf[((size_t)b * C_ + o) * C_ + gd * 16 + dloc] = (unsigned short)f2bf(s * invN);
    }
}

// -------- pass 3: out_b = M_b @ X_b via bf16 MFMA, operand-swapped (R9) --------
// mfma(xfrag, mfrag): lane's 4 acc values = 4 consecutive n at fixed o ->
// ONE dwordx4 nontemporal store (out is terminal; keep x in L3).
__global__ __launch_bounds__(256, 4)
void out_kernel(const float* __restrict__ x, const unsigned short* __restrict__ Mbf,
                float* __restrict__ out) {
    __shared__ unsigned short Xt[256][SROW];   // 36 KiB
    const int t = threadIdx.x, l = t & 63, w = t >> 6;
    const int b = blockIdx.y, n0 = blockIdx.x * 256;
    const float* xb = x + (size_t)b * (C_ * (size_t)N_);
    const int row = l & 15, kg = l >> 4;

    // M fragments: lane l -> M[16g+row][ks*32 + kg*8 + j]  (used as B operand)
    bf16x8 mfrag[2][4];
    #pragma unroll
    for (int ks = 0; ks < 2; ++ks)
        #pragma unroll
        for (int g = 0; g < 4; ++g)
            mfrag[ks][g] = *(const bf16x8*)((const short*)Mbf +
                ((size_t)b * C_ + 16 * g + row) * C_ + ks * 32 + kg * 8);

    // stage+transpose: thread t -> d-quad d0 = (t&15)*4, n-block = (t>>4)*16,
    // two 8-n halves to bound register pressure; ds_write_b64 packs 4 d's.
    const int d0 = (t & 15) * 4, nb2 = (t >> 4) * 16;
    #pragma unroll
    for (int p = 0; p < 2; ++p) {
        const int n8 = nb2 + p * 8;
        float a[4][8];
        #pragma unroll
        for (int r = 0; r < 4; ++r) {
            const float* src = xb + (size_t)(d0 + r) * N_ + n0 + n8;
            float4 q0 = *(const float4*)src;
            float4 q1 = *(const float4*)(src + 4);
            a[r][0] = q0.x; a[r][1] = q0.y; a[r][2] = q0.z; a[r][3] = q0.w;
            a[r][4] = q1.x; a[r][5] = q1.y; a[r][6] = q1.z; a[r][7] = q1.w;
        }
        #pragma unroll
        for (int j = 0; j < 8; ++j) {
            s16x4 pk;
            pk[0] = f2bf(a[0][j]); pk[1] = f2bf(a[1][j]);
            pk[2] = f2bf(a[2][j]); pk[3] = f2bf(a[3][j]);
            *(s16x4*)&Xt[n8 + j][d0] = pk;
        }
    }
    __syncthreads();

    float* ob = out + (size_t)b * (C_ * (size_t)N_);
    #pragma unroll
    for (int nt = 0; nt < 4; ++nt) {
        const int ntile = w * 4 + nt;
        bf16x8 xfrag0 = *(const bf16x8*)&Xt[ntile * 16 + row][kg * 8];
        bf16x8 xfrag1 = *(const bf16x8*)&Xt[ntile * 16 + row][32 + kg * 8];
        #pragma unroll
        for (int g = 0; g < 4; ++g) {
            f32x4 acc = {};
            acc = __builtin_amdgcn_mfma_f32_16x16x32_bf16(xfrag0, mfrag[0][g], acc, 0, 0, 0);
            acc = __builtin_amdgcn_mfma_f32_16x16x32_bf16(xfrag1, mfrag[1][g], acc, 0, 0, 0);
            __builtin_nontemporal_store(acc,
                (f32x4*)&ob[(size_t)(16 * g + row) * N_ + n0 + ntile * 16 + 4 * kg]);
        }
    }
}

extern "C" void kernel_launch(void* const* d_in, const int* in_sizes, int n_in,
                              void* d_out, int out_size, void* d_ws, size_t ws_size,
                              hipStream_t stream) {
    const float* x = (const float*)d_in[0];   // [16,64,128,128] fp32
    const float* w = (const float*)d_in[1];   // [64,64] fp32
    float* out = (float*)d_out;               // [16,64,128,128] fp32

    float* gpart = (float*)d_ws;                                      // 8 MiB
    unsigned short* Mbf = (unsigned short*)(gpart + (size_t)B_ * KCH * 4096);  // 128 KiB

    gram_kernel<<<dim3(KCH, B_), 256, 0, stream>>>(x, gpart);
    rm_kernel<<<dim3(4, B_), 256, 0, stream>>>(w, gpart, Mbf);
    out_kernel<<<dim3(N_ / 256, B_), 256, 0, stream>>>(x, Mbf, out);
}